// Round 14
// baseline (488.832 us; speedup 1.0000x reference)
//
#include <hip/hip_runtime.h>

// Problem constants
#define H_    128
#define W_    128
#define C_    3
#define PAD_  10
#define LWID  117          // LW = LH = 117
#define L_    13689        // LH*LW
#define LPAD  13696        // 107 * 128
#define D_    3072         // C*KH*KW
#define NMEM_ 4096

#define T_MARGIN 3.0f      // candidate margin; i8-quant score err sigma ~0.32 (9 sigma)
#define CAP_     256       // per-row candidate list capacity
#define SCAP_    64        // rescue shortlist capacity (expected ~1.4)

#define PSCALE 127.0f      // patch quant scale (p in [0,1))
#define MSCALE 32.0f       // mem quant scale (clip +-3.97)
#define INVS   (1.0f / (PSCALE * MSCALE))

// shifted quantized-image table: g_Q[s][c][y][j] = qimg[c][y][j+s]
// (y,j in padded coords, row stride 160, 160 rows; 16 shift copies so any
// 16B window (px+kw0) is a 16-aligned load from copy s=(px+kw0)&15)
#define QROWS 160
#define QSTR  160
#define QPLANE (QROWS * QSTR)          // 25600 per (s,c)

typedef int   intx4   __attribute__((ext_vector_type(4)));
typedef int   intx16  __attribute__((ext_vector_type(16)));

// Static device-side scratch (bss) — no d_ws dependency
__device__ int                g_best[L_];
__device__ int                g_pat[L_];     // mapping[g_best[l]] resolved in rescue
__device__ float              g_bias[NMEM_];
__device__ unsigned           g_max;
__device__ int                g_cnt[LPAD];
__device__ unsigned long long g_list[(size_t)LPAD * CAP_];   // 28 MB
__device__ __align__(16) char g_Q[16 * 3 * QPLANE];          // 1.23 MB
__device__ char               g_B[(size_t)NMEM_ * D_];       // 12.6 MB i8 mem
__device__ float              g_part[4][H_ * W_ * C_];       // fold partials, 786 KB

__device__ __forceinline__ unsigned sortable(float f) {
    unsigned b = __float_as_uint(f);
    return (b & 0x80000000u) ? ~b : (b | 0x80000000u);
}
__device__ __forceinline__ float unsortable(unsigned u) {
    unsigned b = (u & 0x80000000u) ? (u & 0x7FFFFFFFu) : ~u;
    return __uint_as_float(b);
}
__device__ __forceinline__ unsigned long long packkey(float s, int n) {
    // max-key == max score; ties -> smaller n (jnp.argmax first-index)
    return ((unsigned long long)sortable(s) << 32) | (unsigned)(~n);
}

// async global->LDS, 16 bytes per lane (global_load_lds_dwordx4)
__device__ __forceinline__ void gl_lds16(const char* g, char* l) {
    __builtin_amdgcn_global_load_lds(
        (const __attribute__((address_space(1))) unsigned int*)(g),
        (__attribute__((address_space(3))) unsigned int*)(l), 16, 0, 0);
}

__device__ __forceinline__ int pack4(int a, int b, int c, int d) {
    return (a & 255) | ((b & 255) << 8) | ((c & 255) << 16) | ((d & 255) << 24);
}

// ---- fused prep: quantize mem + bias | build g_Q shift table | zero cnts ----
// (round-10 structure, verified): A[l][d] = qimg[c][py+kh][px+kw] is staged
// straight from the 1.2 MB g_Q shift table; no 42 MB g_A materialization.
__global__ __launch_bounds__(256)
void prep(const float* __restrict__ img, const float* __restrict__ mem)
{
    const int b = blockIdx.x;
    if (b < NMEM_) {
        const int n = b;
        const float4* row = (const float4*)(mem + (size_t)n * D_);
        int* q8 = (int*)(g_B + (size_t)n * D_);
        float s = 0.f;
        for (int q = threadIdx.x; q < D_ / 4; q += 256) {
            float4 v = row[q];
            int q0 = __float2int_rn(fminf(fmaxf(v.x * MSCALE, -127.f), 127.f));
            int q1 = __float2int_rn(fminf(fmaxf(v.y * MSCALE, -127.f), 127.f));
            int q2 = __float2int_rn(fminf(fmaxf(v.z * MSCALE, -127.f), 127.f));
            int q3 = __float2int_rn(fminf(fmaxf(v.w * MSCALE, -127.f), 127.f));
            q8[q] = pack4(q0, q1, q2, q3);
            s = fmaf(v.x, v.x, s); s = fmaf(v.y, v.y, s);
            s = fmaf(v.z, v.z, s); s = fmaf(v.w, v.w, s);
        }
        #pragma unroll
        for (int m = 32; m >= 1; m >>= 1) s += __shfl_down(s, m, 64);
        __shared__ float red[4];
        int lane = threadIdx.x & 63, w = threadIdx.x >> 6;
        if (lane == 0) red[w] = s;
        __syncthreads();
        if (threadIdx.x == 0) g_bias[n] = -0.5f * (red[0] + red[1] + red[2] + red[3]);
    } else {
        const int bb = b - NMEM_;              // 0..7679 = (s,c,y)
        const int tid = threadIdx.x;
        // zero candidate counters (7680*256 covers LPAD)
        int g = bb * 256 + tid;
        if (g < LPAD) g_cnt[g] = 0;
        if (g == 0) g_max = 0u;
        // build one shift-table row
        const int sft = bb / (3 * QROWS);
        const int rem = bb - sft * (3 * QROWS);
        const int c = rem / QROWS;
        const int y = rem - c * QROWS;
        if (tid < QSTR) {
            const int yy = y - PAD_;
            const int x = tid + sft - PAD_;
            char v = 0;
            if ((unsigned)yy < (unsigned)H_ && (unsigned)x < (unsigned)W_)
                v = (char)__float2int_rn(img[((size_t)yy * W_ + x) * C_ + c] * PSCALE);
            g_Q[(size_t)((sft * 3 + c) * QROWS + y) * QSTR + tid] = v;
        }
    }
}

// ---- i8 MFMA GEMM, 128l x 128n tile, BK=128, 32x32x32 MFMA ------------------
// Round-14: MFMA shape swap (schedule/tiling frozen at r6+r10+r11 config).
// mfma_i32_32x32x32_i8 runs at 4404 TOPS vs 3944 for 16x16x64 (m55/m16) and
// halves MFMA instruction count (16 x ~8.1cyc vs 32 x ~5.1cyc per wave-step).
// LDS bytes and ds_read_b128 count are IDENTICAL (16 reads x 16B); swizzled
// addressing keeps the balanced 8-quad bank pattern; acc stays 64 AGPR
// (2x2 x intx16). Wave tile still 64l x 64n = 2x2 tiles of 32x32, K in 4
// sub-steps of 32 (k-group = ks*2 + (lane>>5)).
// C/D layout (m74/m101, verified): col = lane&31, row = (reg&3) + 8*(reg>>2)
// + 4*(lane>>5). Input frags extend the verified 16x16 pattern: row=lane&31,
// 16B k-group = lane>>5. 32-lane group max still covers the wave's full
// 64-col slice per l-row -> threshold semantics unchanged.
__global__ __launch_bounds__(256, 4)
void gemm_scores()
{
    __shared__ char sA[128 * 128];   // 16 KB
    __shared__ char sB[128 * 128];   // 16 KB
    __shared__ float biasS[128];

    const int tid = threadIdx.x;
    const int b = blockIdx.x;
    const int nt = (b & 7) * 4 + ((b >> 3) & 3);   // 0..31
    const int lt = b >> 5;                          // 0..106
    const int l0 = lt * 128;
    const int n0 = nt * 128;

    if (tid < 128) biasS[tid] = g_bias[n0 + tid];

    const int wave = tid >> 6, lane = tid & 63;
    const int wy = wave >> 1, wx = wave & 1;      // wave tile: 64l x 64n
    const int row32 = lane & 31, hi = lane >> 5;  // 32x32 operand coords

    intx16 acc[2][2];
    #pragma unroll
    for (int i = 0; i < 2; i++)
        #pragma unroll
        for (int j = 0; j < 2; j++)
            #pragma unroll
            for (int r = 0; r < 16; r++) acc[i][j][r] = 0;

    const char* Bb = g_B + (size_t)n0 * D_;

    // per-chunk initial A offset into g_Q (at d0=0: cch=0, kh=dA>>5, kw0=dA&31
    // with dA = jj*16 < 128), then advance incrementally per K-step (r11).
    unsigned offA[4];
    #pragma unroll
    for (int t = 0; t < 4; t++) {
        int c = tid + 256 * t;
        int row = c >> 3;
        int jj = (c & 7) ^ (row & 7);
        int l = l0 + row;
        int py = l / LWID, px = l - py * LWID;
        int dA = jj * 16;
        int kh = dA >> 5;              // 0..3
        int kw0 = dA & 31;             // 0 or 16
        int o = px + kw0;
        int s = o & 15;
        offA[t] = (unsigned)(((s * 3) * QROWS + (py + kh)) * QSTR + (o - s));
    }

    for (int d0 = 0; d0 < D_; d0 += 128) {
        __syncthreads();
        // A from g_Q via incremental offsets (16-aligned by construction)
        #pragma unroll
        for (int t = 0; t < 4; t++)
            gl_lds16(g_Q + offA[t], &sA[(tid + 256 * t) * 16]);
        // B from g_B (compiler strength-reduces d0)
        #pragma unroll
        for (int t = 0; t < 4; t++) {
            int c = tid + 256 * t;
            int row = c >> 3;
            int jj = (c & 7) ^ (row & 7);
            gl_lds16(Bb + (size_t)row * D_ + d0 + jj * 16, &sB[c * 16]);
        }
        // advance A offsets: uniform scalar select (640 in-block, 21120 at
        // the c-block boundary step d0 = 1024k + 896)
        const unsigned stepA = ((d0 & 1023) == 896) ? 21120u : 640u;
        #pragma unroll
        for (int t = 0; t < 4; t++) offA[t] += stepA;
        __syncthreads();

        #pragma unroll
        for (int ks = 0; ks < 4; ks++) {
            const int kg = ks * 2 + hi;            // 16B k-group 0..7
            intx4 a[2], bf[2];
            #pragma unroll
            for (int i = 0; i < 2; i++) {
                int ra = wy * 64 + i * 32 + row32;
                int ca = ra * 8 + (kg ^ (ra & 7));
                a[i] = *(const intx4*)&sA[ca * 16];
            }
            #pragma unroll
            for (int j = 0; j < 2; j++) {
                int rb = wx * 64 + j * 32 + row32;
                int cb = rb * 8 + (kg ^ (rb & 7));
                bf[j] = *(const intx4*)&sB[cb * 16];
            }
            #pragma unroll
            for (int i = 0; i < 2; i++)
                #pragma unroll
                for (int j = 0; j < 2; j++)
                    acc[i][j] = __builtin_amdgcn_mfma_i32_32x32x32_i8(a[i], bf[j], acc[i][j], 0, 0, 0);
        }
    }

    // epilogue. 32x32 C/D layout: col = lane&31, row = (r&3)+8*(r>>2)+4*hi.
    // 32-lane group max covers this wave's full 64-col n-slice per l-row;
    // threshold is a per-slice lower bound of the row max (extra candidates
    // pruned in reduce_rescue against the global row max — semantics same).
    #pragma unroll
    for (int i = 0; i < 2; i++) {
        #pragma unroll
        for (int r = 0; r < 16; r++) {
            const int lrow = l0 + wy * 64 + i * 32 + (r & 3) + 8 * (r >> 2) + 4 * hi;
            float sc[2];
            #pragma unroll
            for (int j = 0; j < 2; j++)
                sc[j] = (float)acc[i][j][r] * INVS + biasS[wx * 64 + j * 32 + row32];
            float bestv = sc[0]; int bestj = 0;
            if (sc[1] > bestv) { bestv = sc[1]; bestj = 1; }
            unsigned long long key = packkey(bestv, n0 + wx * 64 + bestj * 32 + row32);
            // 32-lane group max (lanes with same hi share lrow)
            #pragma unroll
            for (int m = 1; m < 32; m <<= 1) {
                unsigned long long o = __shfl_xor(key, m, 64);
                if (o > key) key = o;
            }
            float thr = unsortable((unsigned)(key >> 32)) - T_MARGIN;
            #pragma unroll
            for (int j = 0; j < 2; j++) {
                if (sc[j] >= thr) {
                    int pos = atomicAdd(&g_cnt[lrow], 1);
                    if (pos < CAP_)
                        g_list[(size_t)lrow * CAP_ + pos] =
                            packkey(sc[j], n0 + wx * 64 + j * 32 + row32);
                }
            }
        }
    }
}

// ---- per-row shortlist + exact fp32 rescore + pattern resolve ---------------
// Single-wave rows, barrier-free (r13): wave-strided list max + shfl butterfly,
// ballot/popc shortlist compaction, kk==1 early exit (bit-identical), LDS
// patch staged once for multi-candidate rows.
__global__ __launch_bounds__(64)
void reduce_rescue(const float* __restrict__ img, const float* __restrict__ mem,
                   const int* __restrict__ mapping)
{
    const int l = blockIdx.x;
    const int lane = threadIdx.x;          // 0..63

    __shared__ int   scand[SCAP_];
    __shared__ float patch[D_];            // 12 KB staged fp32 patch

    const int cnt = g_cnt[l];
    const bool full = cnt > CAP_;
    int kk = 0;

    if (!full) {
        const unsigned long long* lst = g_list + (size_t)l * CAP_;
        unsigned long long mk = 0ull;
        for (int q = lane; q < cnt; q += 64) {
            unsigned long long e = lst[q];
            if (e > mk) mk = e;
        }
        #pragma unroll
        for (int m = 32; m >= 1; m >>= 1) {
            unsigned long long o = __shfl_xor(mk, m, 64);
            if (o > mk) mk = o;
        }
        const float thr = unsortable((unsigned)(mk >> 32)) - T_MARGIN;
        // ballot-prefix shortlist compaction (no atomics, no barriers)
        for (int q0 = 0; q0 < cnt; q0 += 64) {
            int q = q0 + lane;
            bool p = false; int n = 0;
            if (q < cnt) {
                unsigned long long e = lst[q];
                p = unsortable((unsigned)(e >> 32)) >= thr;
                n = (int)(~(unsigned)(e & 0xFFFFFFFFull));
            }
            unsigned long long msk = __ballot(p);
            if (p) {
                int pos = kk + (int)__popcll(msk & ((1ull << lane) - 1ull));
                if (pos < SCAP_) scand[pos] = n;
            }
            kk += (int)__popcll(msk);
        }
        asm volatile("s_waitcnt lgkmcnt(0)" ::: "memory");
        // single survivor IS the argmax (exact semantics)
        if (kk == 1) {
            if (lane == 0) { int n = scand[0]; g_best[l] = n; g_pat[l] = mapping[n]; }
            return;
        }
    }

    const bool scanall = full || (kk > SCAP_);
    const int kn = scanall ? NMEM_ : kk;

    // stage fp32 patch once (torch-unfold order: d = c*1024 + kh*32 + kw)
    const int py = l / LWID, px = l - (l / LWID) * LWID;
    for (int d = lane; d < D_; d += 64) {
        int c = d >> 10, rem = d & 1023, kh = rem >> 5, kw = rem & 31;
        int y = py + kh - PAD_, x = px + kw - PAD_;
        patch[d] = ((unsigned)y < (unsigned)H_ && (unsigned)x < (unsigned)W_)
                   ? img[((size_t)y * W_ + x) * C_ + c] : 0.f;
    }
    asm volatile("s_waitcnt lgkmcnt(0)" ::: "memory");

    // sequential candidates, coalesced wave-dot each (kk ~ 2 typical)
    const float4* pp = (const float4*)patch;
    unsigned long long bk = 0ull;
    for (int q = 0; q < kn; ++q) {
        int n = scanall ? q : scand[q];
        const float4* mr = (const float4*)(mem + (size_t)n * D_);
        float s = 0.f;
        #pragma unroll
        for (int i = 0; i < 12; i++) {
            float4 m4 = mr[i * 64 + lane];
            float4 p4 = pp[i * 64 + lane];
            s = fmaf(m4.x, p4.x, s); s = fmaf(m4.y, p4.y, s);
            s = fmaf(m4.z, p4.z, s); s = fmaf(m4.w, p4.w, s);
        }
        #pragma unroll
        for (int sh = 32; sh >= 1; sh >>= 1) s += __shfl_xor(s, sh, 64);
        unsigned long long key = packkey(s + g_bias[n], n);
        if (key > bk) bk = key;
    }
    if (lane == 0) {
        int n = (int)(~(unsigned)(bk & 0xFFFFFFFFull));
        g_best[l] = n; g_pat[l] = mapping[n];
    }
}

// ---- gather-fold: paired-s full-lane iteration (r12, verified) --------------
__global__ __launch_bounds__(128)
void gather_fold(const float* __restrict__ mem2)
{
    const int y = blockIdx.x;
    const int c = blockIdx.y;
    const int q = blockIdx.z;
    const int x = threadIdx.x;            // 0..127
    const int wv = x >> 6;

    const int py_lo = max(0, y - 21);
    const int py_hi = min(LWID - 1, y + PAD_);
    const int p0 = py_lo + q * 8;
    const int p1 = min(p0 + 8, py_hi + 1);
    const int nrows = (p1 > p0) ? (p1 - p0) : 0;

    __shared__ int patS[8 * LWID];
    for (int i = x; i < nrows * LWID; i += 128) {
        int rr = i / LWID, cc = i - rr * LWID;
        patS[i] = g_pat[(p0 + rr) * LWID + cc];
    }
    __syncthreads();

    const int slo = wv ? 43 : 0;          // wave s-range: [slo, slo+73], paired

    float acc = 0.f;
    for (int py = p0; py < p1; ++py) {
        const int kh = y + PAD_ - py;                 // 0..31
        const int dbase = c * 1024 + kh * 32;
        const int* prow = &patS[(py - p0) * LWID];
        for (int i = 0; i < 37; ++i) {
            int s = slo + i;
            int t = x + PAD_ - s;
            int hi = (t >= 37) ? 37 : 0;
            int d = t - hi;
            if ((unsigned)d < 32u)
                acc += mem2[(size_t)prow[s + hi] * D_ + dbase + d];
        }
    }
    g_part[q][((size_t)y * W_ + x) * C_ + c] = acc;
}

// ---- sum partials + global max ----------------------------------------------
__global__ __launch_bounds__(256)
void maxfind(float* __restrict__ out)
{
    int i = blockIdx.x * 256 + threadIdx.x;           // 192*256 == 49152 exact
    float v = g_part[0][i] + g_part[1][i] + g_part[2][i] + g_part[3][i];
    out[i] = v;
    float m = v;
    #pragma unroll
    for (int s = 32; s >= 1; s >>= 1) m = fmaxf(m, __shfl_xor(m, s, 64));
    if ((threadIdx.x & 63) == 0) atomicMax(&g_max, sortable(m));
}

__global__ __launch_bounds__(256)
void normalize_k(float* __restrict__ out)
{
    int i = blockIdx.x * 256 + threadIdx.x;
    float mx = unsortable(g_max);
    out[i] = out[i] / mx;
}

extern "C" void kernel_launch(void* const* d_in, const int* in_sizes, int n_in,
                              void* d_out, int out_size, void* d_ws, size_t ws_size,
                              hipStream_t stream)
{
    const float* img     = (const float*)d_in[0];   // (128,128,3)
    const float* mem     = (const float*)d_in[1];   // (4096,3072)
    const float* mem2    = (const float*)d_in[2];   // (4096,3072)
    const int*   mapping = (const int*)d_in[3];     // (4096,)
    float* out = (float*)d_out;                     // (128,128,3)

    prep<<<NMEM_ + 16 * 3 * QROWS, 256, 0, stream>>>(img, mem);
    gemm_scores<<<(NMEM_ / 128) * (LPAD / 128), 256, 0, stream>>>();
    reduce_rescue<<<L_, 64, 0, stream>>>(img, mem, mapping);
    gather_fold<<<dim3(H_, C_, 4), 128, 0, stream>>>(mem2);
    maxfind<<<192, 256, 0, stream>>>(out);
    normalize_k<<<192, 256, 0, stream>>>(out);
}

// Round 15
// 427.882 us; speedup vs baseline: 1.1424x; 1.1424x over previous
//
#include <hip/hip_runtime.h>

// Problem constants
#define H_    128
#define W_    128
#define C_    3
#define PAD_  10
#define LWID  117          // LW = LH = 117
#define L_    13689        // LH*LW
#define LPAD  13696        // 107 * 128
#define D_    3072         // C*KH*KW
#define NMEM_ 4096

#define T_MARGIN 3.0f      // candidate margin; i8-quant score err sigma ~0.32 (9 sigma)
#define CAP_     256       // per-row candidate list capacity
#define SCAP_    64        // rescue shortlist capacity (expected ~1.4)

#define PSCALE 127.0f      // patch quant scale (p in [0,1))
#define MSCALE 32.0f       // mem quant scale (clip +-3.97)
#define INVS   (1.0f / (PSCALE * MSCALE))

// shifted quantized-image table: g_Q[s][c][y][j] = qimg[c][y][j+s]
// (y,j in padded coords, row stride 160, 160 rows; 16 shift copies so any
// 16B window (px+kw0) is a 16-aligned load from copy s=(px+kw0)&15)
#define QROWS 160
#define QSTR  160
#define QPLANE (QROWS * QSTR)          // 25600 per (s,c)

typedef int   intx4  __attribute__((ext_vector_type(4)));

// Static device-side scratch (bss) — no d_ws dependency
__device__ int                g_best[L_];
__device__ int                g_pat[L_];     // mapping[g_best[l]] resolved in rescue
__device__ float              g_bias[NMEM_];
__device__ unsigned           g_max;
__device__ int                g_cnt[LPAD];
__device__ unsigned long long g_list[(size_t)LPAD * CAP_];   // 28 MB
__device__ __align__(16) char g_Q[16 * 3 * QPLANE];          // 1.23 MB
__device__ char               g_B[(size_t)NMEM_ * D_];       // 12.6 MB i8 mem
__device__ float              g_part[4][H_ * W_ * C_];       // fold partials, 786 KB

__device__ __forceinline__ unsigned sortable(float f) {
    unsigned b = __float_as_uint(f);
    return (b & 0x80000000u) ? ~b : (b | 0x80000000u);
}
__device__ __forceinline__ float unsortable(unsigned u) {
    unsigned b = (u & 0x80000000u) ? (u & 0x7FFFFFFFu) : ~u;
    return __uint_as_float(b);
}
__device__ __forceinline__ unsigned long long packkey(float s, int n) {
    // max-key == max score; ties -> smaller n (jnp.argmax first-index)
    return ((unsigned long long)sortable(s) << 32) | (unsigned)(~n);
}

// async global->LDS, 16 bytes per lane (global_load_lds_dwordx4)
__device__ __forceinline__ void gl_lds16(const char* g, char* l) {
    __builtin_amdgcn_global_load_lds(
        (const __attribute__((address_space(1))) unsigned int*)(g),
        (__attribute__((address_space(3))) unsigned int*)(l), 16, 0, 0);
}

__device__ __forceinline__ int pack4(int a, int b, int c, int d) {
    return (a & 255) | ((b & 255) << 8) | ((c & 255) << 16) | ((d & 255) << 24);
}

// ---- fused prep: quantize mem + bias | build g_Q shift table | zero cnts ----
// (round-10 structure, verified): A[l][d] = qimg[c][py+kh][px+kw] is staged
// straight from the 1.2 MB g_Q shift table; no 42 MB g_A materialization.
__global__ __launch_bounds__(256)
void prep(const float* __restrict__ img, const float* __restrict__ mem)
{
    const int b = blockIdx.x;
    if (b < NMEM_) {
        const int n = b;
        const float4* row = (const float4*)(mem + (size_t)n * D_);
        int* q8 = (int*)(g_B + (size_t)n * D_);
        float s = 0.f;
        for (int q = threadIdx.x; q < D_ / 4; q += 256) {
            float4 v = row[q];
            int q0 = __float2int_rn(fminf(fmaxf(v.x * MSCALE, -127.f), 127.f));
            int q1 = __float2int_rn(fminf(fmaxf(v.y * MSCALE, -127.f), 127.f));
            int q2 = __float2int_rn(fminf(fmaxf(v.z * MSCALE, -127.f), 127.f));
            int q3 = __float2int_rn(fminf(fmaxf(v.w * MSCALE, -127.f), 127.f));
            q8[q] = pack4(q0, q1, q2, q3);
            s = fmaf(v.x, v.x, s); s = fmaf(v.y, v.y, s);
            s = fmaf(v.z, v.z, s); s = fmaf(v.w, v.w, s);
        }
        #pragma unroll
        for (int m = 32; m >= 1; m >>= 1) s += __shfl_down(s, m, 64);
        __shared__ float red[4];
        int lane = threadIdx.x & 63, w = threadIdx.x >> 6;
        if (lane == 0) red[w] = s;
        __syncthreads();
        if (threadIdx.x == 0) g_bias[n] = -0.5f * (red[0] + red[1] + red[2] + red[3]);
    } else {
        const int bb = b - NMEM_;              // 0..7679 = (s,c,y)
        const int tid = threadIdx.x;
        // zero candidate counters (7680*256 covers LPAD)
        int g = bb * 256 + tid;
        if (g < LPAD) g_cnt[g] = 0;
        if (g == 0) g_max = 0u;
        // build one shift-table row
        const int sft = bb / (3 * QROWS);
        const int rem = bb - sft * (3 * QROWS);
        const int c = rem / QROWS;
        const int y = rem - c * QROWS;
        if (tid < QSTR) {
            const int yy = y - PAD_;
            const int x = tid + sft - PAD_;
            char v = 0;
            if ((unsigned)yy < (unsigned)H_ && (unsigned)x < (unsigned)W_)
                v = (char)__float2int_rn(img[((size_t)yy * W_ + x) * C_ + c] * PSCALE);
            g_Q[(size_t)((sft * 3 + c) * QROWS + y) * QSTR + tid] = v;
        }
    }
}

// ---- i8 MFMA GEMM, 128l x 128n tile, BK=128, 16x16x64 MFMA ------------------
// REVERTED to the r11 config (249 us) after the r14 32x32 swap regressed
// (conflicts 0 -> 2.1e7: a 32-row/fixed-kg ds_read phase against 128B row
// stride is inherently 4-way bank-aliased — only the 16x16 shape's 16-row
// phases + per-quarter kgrp rotation are conflict-free, and gl_lds16's
// linear-dest rule forbids row padding). Round-15 adds incremental offB
// (B source advances exactly +128 B/step), completing the r11 addressing
// cleanup. Schedule/tiling otherwise frozen: 7 structural variants lost.
__global__ __launch_bounds__(256, 4)
void gemm_scores()
{
    __shared__ char sA[128 * 128];   // 16 KB
    __shared__ char sB[128 * 128];   // 16 KB
    __shared__ float biasS[128];

    const int tid = threadIdx.x;
    const int b = blockIdx.x;
    const int nt = (b & 7) * 4 + ((b >> 3) & 3);   // 0..31
    const int lt = b >> 5;                          // 0..106
    const int l0 = lt * 128;
    const int n0 = nt * 128;

    if (tid < 128) biasS[tid] = g_bias[n0 + tid];

    const int wave = tid >> 6, lane = tid & 63;
    const int wy = wave >> 1, wx = wave & 1;      // wave tile: 64l x 64n
    const int mrow = lane & 15, kgrp = lane >> 4;

    intx4 acc[4][4];
    #pragma unroll
    for (int i = 0; i < 4; i++)
        #pragma unroll
        for (int j = 0; j < 4; j++) acc[i][j] = (intx4){0, 0, 0, 0};

    const char* Bb = g_B + (size_t)n0 * D_;

    // per-chunk initial offsets; both sources are affine in the K-step:
    // A: +640 B in-block, +21120 B at c-block boundary (d0&1023 == 896);
    // B: +128 B always.
    unsigned offA[4], offB[4];
    #pragma unroll
    for (int t = 0; t < 4; t++) {
        int c = tid + 256 * t;
        int row = c >> 3;
        int jj = (c & 7) ^ (row & 7);
        int l = l0 + row;
        int py = l / LWID, px = l - py * LWID;
        int dA = jj * 16;
        int kh = dA >> 5;              // 0..3
        int kw0 = dA & 31;             // 0 or 16
        int o = px + kw0;
        int s = o & 15;
        offA[t] = (unsigned)(((s * 3) * QROWS + (py + kh)) * QSTR + (o - s));
        offB[t] = (unsigned)(row * D_ + jj * 16);
    }

    for (int d0 = 0; d0 < D_; d0 += 128) {
        __syncthreads();
        // A from g_Q, B from g_B via incremental offsets (16-aligned)
        #pragma unroll
        for (int t = 0; t < 4; t++)
            gl_lds16(g_Q + offA[t], &sA[(tid + 256 * t) * 16]);
        #pragma unroll
        for (int t = 0; t < 4; t++)
            gl_lds16(Bb + offB[t], &sB[(tid + 256 * t) * 16]);
        // advance: A uniform scalar select; B always +128
        const unsigned stepA = ((d0 & 1023) == 896) ? 21120u : 640u;
        #pragma unroll
        for (int t = 0; t < 4; t++) { offA[t] += stepA; offB[t] += 128u; }
        __syncthreads();

        #pragma unroll
        for (int ks = 0; ks < 2; ks++) {
            intx4 a[4], bf[4];
            #pragma unroll
            for (int i = 0; i < 4; i++) {
                int ra = wy * 64 + i * 16 + mrow;
                int ca = ra * 8 + ((ks * 4 + kgrp) ^ (ra & 7));
                a[i] = *(const intx4*)&sA[ca * 16];
            }
            #pragma unroll
            for (int j = 0; j < 4; j++) {
                int rb = wx * 64 + j * 16 + mrow;
                int cb = rb * 8 + ((ks * 4 + kgrp) ^ (rb & 7));
                bf[j] = *(const intx4*)&sB[cb * 16];
            }
            #pragma unroll
            for (int i = 0; i < 4; i++)
                #pragma unroll
                for (int j = 0; j < 4; j++)
                    acc[i][j] = __builtin_amdgcn_mfma_i32_16x16x64_i8(a[i], bf[j], acc[i][j], 0, 0, 0);
        }
    }

    // epilogue. C/D layout: col = lane&15 (mrow), row = kgrp*4 + reg.
    // 16-lane group max covers this wave's full 64-col n-slice; threshold is
    // a per-slice lower bound of the row max (extra candidates are pruned in
    // reduce_rescue against the global row max — semantics unchanged).
    #pragma unroll
    for (int i = 0; i < 4; i++) {
        #pragma unroll
        for (int r = 0; r < 4; r++) {
            const int lrow = l0 + wy * 64 + i * 16 + kgrp * 4 + r;
            float sc[4];
            #pragma unroll
            for (int j = 0; j < 4; j++)
                sc[j] = (float)acc[i][j][r] * INVS + biasS[wx * 64 + j * 16 + mrow];
            float bestv = sc[0]; int bestj = 0;
            #pragma unroll
            for (int j = 1; j < 4; j++)
                if (sc[j] > bestv) { bestv = sc[j]; bestj = j; }
            unsigned long long key = packkey(bestv, n0 + wx * 64 + bestj * 16 + mrow);
            #pragma unroll
            for (int m = 1; m < 16; m <<= 1) {
                unsigned long long o = __shfl_xor(key, m, 64);
                if (o > key) key = o;
            }
            float thr = unsortable((unsigned)(key >> 32)) - T_MARGIN;
            #pragma unroll
            for (int j = 0; j < 4; j++) {
                if (sc[j] >= thr) {
                    int pos = atomicAdd(&g_cnt[lrow], 1);
                    if (pos < CAP_)
                        g_list[(size_t)lrow * CAP_ + pos] =
                            packkey(sc[j], n0 + wx * 64 + j * 16 + mrow);
                }
            }
        }
    }
}

// ---- per-row shortlist + exact fp32 rescore + pattern resolve ---------------
// Single-wave rows, barrier-free (r13): wave-strided list max + shfl butterfly,
// ballot/popc shortlist compaction, kk==1 early exit (bit-identical), LDS
// patch staged once for multi-candidate rows.
__global__ __launch_bounds__(64)
void reduce_rescue(const float* __restrict__ img, const float* __restrict__ mem,
                   const int* __restrict__ mapping)
{
    const int l = blockIdx.x;
    const int lane = threadIdx.x;          // 0..63

    __shared__ int   scand[SCAP_];
    __shared__ float patch[D_];            // 12 KB staged fp32 patch

    const int cnt = g_cnt[l];
    const bool full = cnt > CAP_;
    int kk = 0;

    if (!full) {
        const unsigned long long* lst = g_list + (size_t)l * CAP_;
        unsigned long long mk = 0ull;
        for (int q = lane; q < cnt; q += 64) {
            unsigned long long e = lst[q];
            if (e > mk) mk = e;
        }
        #pragma unroll
        for (int m = 32; m >= 1; m >>= 1) {
            unsigned long long o = __shfl_xor(mk, m, 64);
            if (o > mk) mk = o;
        }
        const float thr = unsortable((unsigned)(mk >> 32)) - T_MARGIN;
        // ballot-prefix shortlist compaction (no atomics, no barriers)
        for (int q0 = 0; q0 < cnt; q0 += 64) {
            int q = q0 + lane;
            bool p = false; int n = 0;
            if (q < cnt) {
                unsigned long long e = lst[q];
                p = unsortable((unsigned)(e >> 32)) >= thr;
                n = (int)(~(unsigned)(e & 0xFFFFFFFFull));
            }
            unsigned long long msk = __ballot(p);
            if (p) {
                int pos = kk + (int)__popcll(msk & ((1ull << lane) - 1ull));
                if (pos < SCAP_) scand[pos] = n;
            }
            kk += (int)__popcll(msk);
        }
        asm volatile("s_waitcnt lgkmcnt(0)" ::: "memory");
        // single survivor IS the argmax (exact semantics)
        if (kk == 1) {
            if (lane == 0) { int n = scand[0]; g_best[l] = n; g_pat[l] = mapping[n]; }
            return;
        }
    }

    const bool scanall = full || (kk > SCAP_);
    const int kn = scanall ? NMEM_ : kk;

    // stage fp32 patch once (torch-unfold order: d = c*1024 + kh*32 + kw)
    const int py = l / LWID, px = l - (l / LWID) * LWID;
    for (int d = lane; d < D_; d += 64) {
        int c = d >> 10, rem = d & 1023, kh = rem >> 5, kw = rem & 31;
        int y = py + kh - PAD_, x = px + kw - PAD_;
        patch[d] = ((unsigned)y < (unsigned)H_ && (unsigned)x < (unsigned)W_)
                   ? img[((size_t)y * W_ + x) * C_ + c] : 0.f;
    }
    asm volatile("s_waitcnt lgkmcnt(0)" ::: "memory");

    // sequential candidates, coalesced wave-dot each (kk ~ 2 typical)
    const float4* pp = (const float4*)patch;
    unsigned long long bk = 0ull;
    for (int q = 0; q < kn; ++q) {
        int n = scanall ? q : scand[q];
        const float4* mr = (const float4*)(mem + (size_t)n * D_);
        float s = 0.f;
        #pragma unroll
        for (int i = 0; i < 12; i++) {
            float4 m4 = mr[i * 64 + lane];
            float4 p4 = pp[i * 64 + lane];
            s = fmaf(m4.x, p4.x, s); s = fmaf(m4.y, p4.y, s);
            s = fmaf(m4.z, p4.z, s); s = fmaf(m4.w, p4.w, s);
        }
        #pragma unroll
        for (int sh = 32; sh >= 1; sh >>= 1) s += __shfl_xor(s, sh, 64);
        unsigned long long key = packkey(s + g_bias[n], n);
        if (key > bk) bk = key;
    }
    if (lane == 0) {
        int n = (int)(~(unsigned)(bk & 0xFFFFFFFFull));
        g_best[l] = n; g_pat[l] = mapping[n];
    }
}

// ---- gather-fold: paired-s full-lane iteration (r12, verified) --------------
__global__ __launch_bounds__(128)
void gather_fold(const float* __restrict__ mem2)
{
    const int y = blockIdx.x;
    const int c = blockIdx.y;
    const int q = blockIdx.z;
    const int x = threadIdx.x;            // 0..127
    const int wv = x >> 6;

    const int py_lo = max(0, y - 21);
    const int py_hi = min(LWID - 1, y + PAD_);
    const int p0 = py_lo + q * 8;
    const int p1 = min(p0 + 8, py_hi + 1);
    const int nrows = (p1 > p0) ? (p1 - p0) : 0;

    __shared__ int patS[8 * LWID];
    for (int i = x; i < nrows * LWID; i += 128) {
        int rr = i / LWID, cc = i - rr * LWID;
        patS[i] = g_pat[(p0 + rr) * LWID + cc];
    }
    __syncthreads();

    const int slo = wv ? 43 : 0;          // wave s-range: [slo, slo+73], paired

    float acc = 0.f;
    for (int py = p0; py < p1; ++py) {
        const int kh = y + PAD_ - py;                 // 0..31
        const int dbase = c * 1024 + kh * 32;
        const int* prow = &patS[(py - p0) * LWID];
        for (int i = 0; i < 37; ++i) {
            int s = slo + i;
            int t = x + PAD_ - s;
            int hi = (t >= 37) ? 37 : 0;
            int d = t - hi;
            if ((unsigned)d < 32u)
                acc += mem2[(size_t)prow[s + hi] * D_ + dbase + d];
        }
    }
    g_part[q][((size_t)y * W_ + x) * C_ + c] = acc;
}

// ---- sum partials + global max ----------------------------------------------
__global__ __launch_bounds__(256)
void maxfind(float* __restrict__ out)
{
    int i = blockIdx.x * 256 + threadIdx.x;           // 192*256 == 49152 exact
    float v = g_part[0][i] + g_part[1][i] + g_part[2][i] + g_part[3][i];
    out[i] = v;
    float m = v;
    #pragma unroll
    for (int s = 32; s >= 1; s >>= 1) m = fmaxf(m, __shfl_xor(m, s, 64));
    if ((threadIdx.x & 63) == 0) atomicMax(&g_max, sortable(m));
}

__global__ __launch_bounds__(256)
void normalize_k(float* __restrict__ out)
{
    int i = blockIdx.x * 256 + threadIdx.x;
    float mx = unsortable(g_max);
    out[i] = out[i] / mx;
}

extern "C" void kernel_launch(void* const* d_in, const int* in_sizes, int n_in,
                              void* d_out, int out_size, void* d_ws, size_t ws_size,
                              hipStream_t stream)
{
    const float* img     = (const float*)d_in[0];   // (128,128,3)
    const float* mem     = (const float*)d_in[1];   // (4096,3072)
    const float* mem2    = (const float*)d_in[2];   // (4096,3072)
    const int*   mapping = (const int*)d_in[3];     // (4096,)
    float* out = (float*)d_out;                     // (128,128,3)

    prep<<<NMEM_ + 16 * 3 * QROWS, 256, 0, stream>>>(img, mem);
    gemm_scores<<<(NMEM_ / 128) * (LPAD / 128), 256, 0, stream>>>();
    reduce_rescue<<<L_, 64, 0, stream>>>(img, mem, mapping);
    gather_fold<<<dim3(H_, C_, 4), 128, 0, stream>>>(mem2);
    maxfind<<<192, 256, 0, stream>>>(out);
    normalize_k<<<192, 256, 0, stream>>>(out);
}

// Round 16
// 410.289 us; speedup vs baseline: 1.1914x; 1.0429x over previous
//
#include <hip/hip_runtime.h>

// Problem constants
#define H_    128
#define W_    128
#define C_    3
#define PAD_  10
#define LWID  117          // LW = LH = 117
#define L_    13689        // LH*LW
#define LPAD  13696        // 107 * 128
#define D_    3072         // C*KH*KW
#define NMEM_ 4096

#define T_MARGIN 3.0f      // candidate margin; i8-quant score err sigma ~0.32 (9 sigma)
#define CAP_     256       // per-row candidate list capacity
#define SCAP_    64        // rescue shortlist capacity (expected ~1.4)

#define PSCALE 127.0f      // patch quant scale (p in [0,1))
#define MSCALE 32.0f       // mem quant scale (clip +-3.97)
#define INVS   (1.0f / (PSCALE * MSCALE))

// shifted quantized-image table: g_Q[s][c][y][j] = qimg[c][y][j+s]
// (y,j in padded coords, row stride 160, 160 rows; 16 shift copies so any
// 16B window (px+kw0) is a 16-aligned load from copy s=(px+kw0)&15)
#define QROWS 160
#define QSTR  160
#define QPLANE (QROWS * QSTR)          // 25600 per (s,c)

typedef int   intx4  __attribute__((ext_vector_type(4)));

// Static device-side scratch (bss) — no d_ws dependency
__device__ int                g_best[L_];
__device__ int                g_pat[L_];     // mapping[g_best[l]] resolved in rescue
__device__ float              g_bias[NMEM_];
__device__ unsigned           g_max;
__device__ int                g_cnt[LPAD];
__device__ unsigned long long g_list[(size_t)LPAD * CAP_];   // 28 MB
__device__ __align__(16) char g_Q[16 * 3 * QPLANE];          // 1.23 MB
__device__ char               g_B[(size_t)NMEM_ * D_];       // 12.6 MB i8 mem
__device__ float              g_part[8][H_ * W_ * C_];       // fold partials, 1.57 MB

__device__ __forceinline__ unsigned sortable(float f) {
    unsigned b = __float_as_uint(f);
    return (b & 0x80000000u) ? ~b : (b | 0x80000000u);
}
__device__ __forceinline__ float unsortable(unsigned u) {
    unsigned b = (u & 0x80000000u) ? (u & 0x7FFFFFFFu) : ~u;
    return __uint_as_float(b);
}
__device__ __forceinline__ unsigned long long packkey(float s, int n) {
    // max-key == max score; ties -> smaller n (jnp.argmax first-index)
    return ((unsigned long long)sortable(s) << 32) | (unsigned)(~n);
}

// async global->LDS, 16 bytes per lane (global_load_lds_dwordx4)
__device__ __forceinline__ void gl_lds16(const char* g, char* l) {
    __builtin_amdgcn_global_load_lds(
        (const __attribute__((address_space(1))) unsigned int*)(g),
        (__attribute__((address_space(3))) unsigned int*)(l), 16, 0, 0);
}

__device__ __forceinline__ int pack4(int a, int b, int c, int d) {
    return (a & 255) | ((b & 255) << 8) | ((c & 255) << 16) | ((d & 255) << 24);
}

// ---- fused prep: quantize mem + bias | build g_Q shift table | zero cnts ----
// (round-10 structure, verified): A[l][d] = qimg[c][py+kh][px+kw] is staged
// straight from the 1.2 MB g_Q shift table; no 42 MB g_A materialization.
__global__ __launch_bounds__(256)
void prep(const float* __restrict__ img, const float* __restrict__ mem)
{
    const int b = blockIdx.x;
    if (b < NMEM_) {
        const int n = b;
        const float4* row = (const float4*)(mem + (size_t)n * D_);
        int* q8 = (int*)(g_B + (size_t)n * D_);
        float s = 0.f;
        for (int q = threadIdx.x; q < D_ / 4; q += 256) {
            float4 v = row[q];
            int q0 = __float2int_rn(fminf(fmaxf(v.x * MSCALE, -127.f), 127.f));
            int q1 = __float2int_rn(fminf(fmaxf(v.y * MSCALE, -127.f), 127.f));
            int q2 = __float2int_rn(fminf(fmaxf(v.z * MSCALE, -127.f), 127.f));
            int q3 = __float2int_rn(fminf(fmaxf(v.w * MSCALE, -127.f), 127.f));
            q8[q] = pack4(q0, q1, q2, q3);
            s = fmaf(v.x, v.x, s); s = fmaf(v.y, v.y, s);
            s = fmaf(v.z, v.z, s); s = fmaf(v.w, v.w, s);
        }
        #pragma unroll
        for (int m = 32; m >= 1; m >>= 1) s += __shfl_down(s, m, 64);
        __shared__ float red[4];
        int lane = threadIdx.x & 63, w = threadIdx.x >> 6;
        if (lane == 0) red[w] = s;
        __syncthreads();
        if (threadIdx.x == 0) g_bias[n] = -0.5f * (red[0] + red[1] + red[2] + red[3]);
    } else {
        const int bb = b - NMEM_;              // 0..7679 = (s,c,y)
        const int tid = threadIdx.x;
        // zero candidate counters (7680*256 covers LPAD)
        int g = bb * 256 + tid;
        if (g < LPAD) g_cnt[g] = 0;
        if (g == 0) g_max = 0u;
        // build one shift-table row
        const int sft = bb / (3 * QROWS);
        const int rem = bb - sft * (3 * QROWS);
        const int c = rem / QROWS;
        const int y = rem - c * QROWS;
        if (tid < QSTR) {
            const int yy = y - PAD_;
            const int x = tid + sft - PAD_;
            char v = 0;
            if ((unsigned)yy < (unsigned)H_ && (unsigned)x < (unsigned)W_)
                v = (char)__float2int_rn(img[((size_t)yy * W_ + x) * C_ + c] * PSCALE);
            g_Q[(size_t)((sft * 3 + c) * QROWS + y) * QSTR + tid] = v;
        }
    }
}

// ---- i8 MFMA GEMM, 128l x 128n tile, BK=128, 16x16x64 MFMA ------------------
// FROZEN (r11+r15 config, ~250 us). Session evidence: 2 paying levers
// (4 blk/CU occupancy r6: 298->277; g_Q A-source r10/r11: 277->250), 8
// structural variants null or worse (coarse dbuf r1 320, 4-phase r3 315,
// A-in-reg r5 372, BN=64 r7 491, BK=64 dbuf r9 357, 32x32 MFMA r14 311,
// offB r15 null). Conflict-free LDS requires the 16x16 shape + 128B rows +
// linear gl_lds dest; occupancy is reg-capped at 16 waves/CU by the 64-AGPR
// accumulator. Do not touch without new counter evidence.
__global__ __launch_bounds__(256, 4)
void gemm_scores()
{
    __shared__ char sA[128 * 128];   // 16 KB
    __shared__ char sB[128 * 128];   // 16 KB
    __shared__ float biasS[128];

    const int tid = threadIdx.x;
    const int b = blockIdx.x;
    const int nt = (b & 7) * 4 + ((b >> 3) & 3);   // 0..31
    const int lt = b >> 5;                          // 0..106
    const int l0 = lt * 128;
    const int n0 = nt * 128;

    if (tid < 128) biasS[tid] = g_bias[n0 + tid];

    const int wave = tid >> 6, lane = tid & 63;
    const int wy = wave >> 1, wx = wave & 1;      // wave tile: 64l x 64n
    const int mrow = lane & 15, kgrp = lane >> 4;

    intx4 acc[4][4];
    #pragma unroll
    for (int i = 0; i < 4; i++)
        #pragma unroll
        for (int j = 0; j < 4; j++) acc[i][j] = (intx4){0, 0, 0, 0};

    const char* Bb = g_B + (size_t)n0 * D_;

    // per-chunk initial offsets; both sources are affine in the K-step:
    // A: +640 B in-block, +21120 B at c-block boundary (d0&1023 == 896);
    // B: +128 B always.
    unsigned offA[4], offB[4];
    #pragma unroll
    for (int t = 0; t < 4; t++) {
        int c = tid + 256 * t;
        int row = c >> 3;
        int jj = (c & 7) ^ (row & 7);
        int l = l0 + row;
        int py = l / LWID, px = l - py * LWID;
        int dA = jj * 16;
        int kh = dA >> 5;              // 0..3
        int kw0 = dA & 31;             // 0 or 16
        int o = px + kw0;
        int s = o & 15;
        offA[t] = (unsigned)(((s * 3) * QROWS + (py + kh)) * QSTR + (o - s));
        offB[t] = (unsigned)(row * D_ + jj * 16);
    }

    for (int d0 = 0; d0 < D_; d0 += 128) {
        __syncthreads();
        // A from g_Q, B from g_B via incremental offsets (16-aligned)
        #pragma unroll
        for (int t = 0; t < 4; t++)
            gl_lds16(g_Q + offA[t], &sA[(tid + 256 * t) * 16]);
        #pragma unroll
        for (int t = 0; t < 4; t++)
            gl_lds16(Bb + offB[t], &sB[(tid + 256 * t) * 16]);
        // advance: A uniform scalar select; B always +128
        const unsigned stepA = ((d0 & 1023) == 896) ? 21120u : 640u;
        #pragma unroll
        for (int t = 0; t < 4; t++) { offA[t] += stepA; offB[t] += 128u; }
        __syncthreads();

        #pragma unroll
        for (int ks = 0; ks < 2; ks++) {
            intx4 a[4], bf[4];
            #pragma unroll
            for (int i = 0; i < 4; i++) {
                int ra = wy * 64 + i * 16 + mrow;
                int ca = ra * 8 + ((ks * 4 + kgrp) ^ (ra & 7));
                a[i] = *(const intx4*)&sA[ca * 16];
            }
            #pragma unroll
            for (int j = 0; j < 4; j++) {
                int rb = wx * 64 + j * 16 + mrow;
                int cb = rb * 8 + ((ks * 4 + kgrp) ^ (rb & 7));
                bf[j] = *(const intx4*)&sB[cb * 16];
            }
            #pragma unroll
            for (int i = 0; i < 4; i++)
                #pragma unroll
                for (int j = 0; j < 4; j++)
                    acc[i][j] = __builtin_amdgcn_mfma_i32_16x16x64_i8(a[i], bf[j], acc[i][j], 0, 0, 0);
        }
    }

    // epilogue. C/D layout: col = lane&15 (mrow), row = kgrp*4 + reg.
    // 16-lane group max covers this wave's full 64-col n-slice; threshold is
    // a per-slice lower bound of the row max (extra candidates are pruned in
    // reduce_rescue against the global row max — semantics unchanged).
    #pragma unroll
    for (int i = 0; i < 4; i++) {
        #pragma unroll
        for (int r = 0; r < 4; r++) {
            const int lrow = l0 + wy * 64 + i * 16 + kgrp * 4 + r;
            float sc[4];
            #pragma unroll
            for (int j = 0; j < 4; j++)
                sc[j] = (float)acc[i][j][r] * INVS + biasS[wx * 64 + j * 16 + mrow];
            float bestv = sc[0]; int bestj = 0;
            #pragma unroll
            for (int j = 1; j < 4; j++)
                if (sc[j] > bestv) { bestv = sc[j]; bestj = j; }
            unsigned long long key = packkey(bestv, n0 + wx * 64 + bestj * 16 + mrow);
            #pragma unroll
            for (int m = 1; m < 16; m <<= 1) {
                unsigned long long o = __shfl_xor(key, m, 64);
                if (o > key) key = o;
            }
            float thr = unsortable((unsigned)(key >> 32)) - T_MARGIN;
            #pragma unroll
            for (int j = 0; j < 4; j++) {
                if (sc[j] >= thr) {
                    int pos = atomicAdd(&g_cnt[lrow], 1);
                    if (pos < CAP_)
                        g_list[(size_t)lrow * CAP_ + pos] =
                            packkey(sc[j], n0 + wx * 64 + j * 16 + mrow);
                }
            }
        }
    }
}

// ---- per-row shortlist + exact fp32 rescore + pattern resolve ---------------
// Single-wave rows, barrier-free (r13): wave-strided list max + shfl butterfly,
// ballot/popc shortlist compaction, kk==1 early exit (bit-identical), LDS
// patch staged once for multi-candidate rows.
__global__ __launch_bounds__(64)
void reduce_rescue(const float* __restrict__ img, const float* __restrict__ mem,
                   const int* __restrict__ mapping)
{
    const int l = blockIdx.x;
    const int lane = threadIdx.x;          // 0..63

    __shared__ int   scand[SCAP_];
    __shared__ float patch[D_];            // 12 KB staged fp32 patch

    const int cnt = g_cnt[l];
    const bool full = cnt > CAP_;
    int kk = 0;

    if (!full) {
        const unsigned long long* lst = g_list + (size_t)l * CAP_;
        unsigned long long mk = 0ull;
        for (int q = lane; q < cnt; q += 64) {
            unsigned long long e = lst[q];
            if (e > mk) mk = e;
        }
        #pragma unroll
        for (int m = 32; m >= 1; m >>= 1) {
            unsigned long long o = __shfl_xor(mk, m, 64);
            if (o > mk) mk = o;
        }
        const float thr = unsortable((unsigned)(mk >> 32)) - T_MARGIN;
        // ballot-prefix shortlist compaction (no atomics, no barriers)
        for (int q0 = 0; q0 < cnt; q0 += 64) {
            int q = q0 + lane;
            bool p = false; int n = 0;
            if (q < cnt) {
                unsigned long long e = lst[q];
                p = unsortable((unsigned)(e >> 32)) >= thr;
                n = (int)(~(unsigned)(e & 0xFFFFFFFFull));
            }
            unsigned long long msk = __ballot(p);
            if (p) {
                int pos = kk + (int)__popcll(msk & ((1ull << lane) - 1ull));
                if (pos < SCAP_) scand[pos] = n;
            }
            kk += (int)__popcll(msk);
        }
        asm volatile("s_waitcnt lgkmcnt(0)" ::: "memory");
        // single survivor IS the argmax (exact semantics)
        if (kk == 1) {
            if (lane == 0) { int n = scand[0]; g_best[l] = n; g_pat[l] = mapping[n]; }
            return;
        }
    }

    const bool scanall = full || (kk > SCAP_);
    const int kn = scanall ? NMEM_ : kk;

    // stage fp32 patch once (torch-unfold order: d = c*1024 + kh*32 + kw)
    const int py = l / LWID, px = l - (l / LWID) * LWID;
    for (int d = lane; d < D_; d += 64) {
        int c = d >> 10, rem = d & 1023, kh = rem >> 5, kw = rem & 31;
        int y = py + kh - PAD_, x = px + kw - PAD_;
        patch[d] = ((unsigned)y < (unsigned)H_ && (unsigned)x < (unsigned)W_)
                   ? img[((size_t)y * W_ + x) * C_ + c] : 0.f;
    }
    asm volatile("s_waitcnt lgkmcnt(0)" ::: "memory");

    // sequential candidates, coalesced wave-dot each (kk ~ 2 typical)
    const float4* pp = (const float4*)patch;
    unsigned long long bk = 0ull;
    for (int q = 0; q < kn; ++q) {
        int n = scanall ? q : scand[q];
        const float4* mr = (const float4*)(mem + (size_t)n * D_);
        float s = 0.f;
        #pragma unroll
        for (int i = 0; i < 12; i++) {
            float4 m4 = mr[i * 64 + lane];
            float4 p4 = pp[i * 64 + lane];
            s = fmaf(m4.x, p4.x, s); s = fmaf(m4.y, p4.y, s);
            s = fmaf(m4.z, p4.z, s); s = fmaf(m4.w, p4.w, s);
        }
        #pragma unroll
        for (int sh = 32; sh >= 1; sh >>= 1) s += __shfl_xor(s, sh, 64);
        unsigned long long key = packkey(s + g_bias[n], n);
        if (key > bk) bk = key;
    }
    if (lane == 0) {
        int n = (int)(~(unsigned)(bk & 0xFFFFFFFFull));
        g_best[l] = n; g_pat[l] = mapping[n];
    }
}

// ---- gather-fold: paired-s iteration (r12), py split 8-way (r16) ------------
// Round-16: occupancy/MLP play on the fold. The 48.8M mem2 gathers are
// L3-resident semi-random row reads (~600 cyc); at q=4 the kernel ran 1536
// blocks = 12 waves/CU — too little memory-level parallelism to hide L3
// latency. q=8 (<=4 py-rows per block) -> 3072 blocks = 24 waves/CU,
// doubling in-flight gathers. maxfind sums 8 partials (+0.3 us).
__global__ __launch_bounds__(128)
void gather_fold(const float* __restrict__ mem2)
{
    const int y = blockIdx.x;
    const int c = blockIdx.y;
    const int q = blockIdx.z;             // 0..7
    const int x = threadIdx.x;            // 0..127
    const int wv = x >> 6;

    const int py_lo = max(0, y - 21);
    const int py_hi = min(LWID - 1, y + PAD_);
    const int p0 = py_lo + q * 4;
    const int p1 = min(p0 + 4, py_hi + 1);
    const int nrows = (p1 > p0) ? (p1 - p0) : 0;

    __shared__ int patS[4 * LWID];
    for (int i = x; i < nrows * LWID; i += 128) {
        int rr = i / LWID, cc = i - rr * LWID;
        patS[i] = g_pat[(p0 + rr) * LWID + cc];
    }
    __syncthreads();

    const int slo = wv ? 43 : 0;          // wave s-range: [slo, slo+73], paired

    float acc = 0.f;
    for (int py = p0; py < p1; ++py) {
        const int kh = y + PAD_ - py;                 // 0..31
        const int dbase = c * 1024 + kh * 32;
        const int* prow = &patS[(py - p0) * LWID];
        for (int i = 0; i < 37; ++i) {
            int s = slo + i;
            int t = x + PAD_ - s;
            int hi = (t >= 37) ? 37 : 0;
            int d = t - hi;
            if ((unsigned)d < 32u)
                acc += mem2[(size_t)prow[s + hi] * D_ + dbase + d];
        }
    }
    g_part[q][((size_t)y * W_ + x) * C_ + c] = acc;
}

// ---- sum partials + global max ----------------------------------------------
__global__ __launch_bounds__(256)
void maxfind(float* __restrict__ out)
{
    int i = blockIdx.x * 256 + threadIdx.x;           // 192*256 == 49152 exact
    float v = 0.f;
    #pragma unroll
    for (int k = 0; k < 8; k++) v += g_part[k][i];
    out[i] = v;
    float m = v;
    #pragma unroll
    for (int s = 32; s >= 1; s >>= 1) m = fmaxf(m, __shfl_xor(m, s, 64));
    if ((threadIdx.x & 63) == 0) atomicMax(&g_max, sortable(m));
}

__global__ __launch_bounds__(256)
void normalize_k(float* __restrict__ out)
{
    int i = blockIdx.x * 256 + threadIdx.x;
    float mx = unsortable(g_max);
    out[i] = out[i] / mx;
}

extern "C" void kernel_launch(void* const* d_in, const int* in_sizes, int n_in,
                              void* d_out, int out_size, void* d_ws, size_t ws_size,
                              hipStream_t stream)
{
    const float* img     = (const float*)d_in[0];   // (128,128,3)
    const float* mem     = (const float*)d_in[1];   // (4096,3072)
    const float* mem2    = (const float*)d_in[2];   // (4096,3072)
    const int*   mapping = (const int*)d_in[3];     // (4096,)
    float* out = (float*)d_out;                     // (128,128,3)

    prep<<<NMEM_ + 16 * 3 * QROWS, 256, 0, stream>>>(img, mem);
    gemm_scores<<<(NMEM_ / 128) * (LPAD / 128), 256, 0, stream>>>();
    reduce_rescue<<<L_, 64, 0, stream>>>(img, mem, mapping);
    gather_fold<<<dim3(H_, C_, 8), 128, 0, stream>>>(mem2);
    maxfind<<<192, 256, 0, stream>>>(out);
    normalize_k<<<192, 256, 0, stream>>>(out);
}